// Round 3
// baseline (414.168 us; speedup 1.0000x reference)
//
#include <hip/hip_runtime.h>
#include <hip/hip_fp16.h>

#define N_POINTS 500000
#define BN_EPS 1e-5f
#define A_COEF -0.75f

typedef __attribute__((ext_vector_type(8))) short short8;
typedef __attribute__((ext_vector_type(4))) float floatx4;
typedef unsigned short ushort_t;
typedef unsigned int uint_t;

// -------- workspace layout (float offsets) --------
#define WS_WBF_OFF    0                          // bf16 weights [tap(9)][oc(64)][ic(64)]   : 18432 floats
#define WS_CONV_OFF   18432                      // conv HWC fp32 [3][128][128][64]          : 3145728
#define WS_SUM_OFF    (WS_CONV_OFF + 3145728)    // [3][64]
#define WS_SUMSQ_OFF  (WS_SUM_OFF + 192)
#define WS_SCALE_OFF  (WS_SUMSQ_OFF + 192)
#define WS_SHIFT_OFF  (WS_SCALE_OFF + 192)
#define WS_PLANES_OFF (WS_SHIFT_OFF + 192)       // fp16 planes HWC [3][128][128][64]        : 1572864 floats
#define WS_INBF_OFF   (WS_PLANES_OFF + 1572864)  // bf16 input HWC [3][256][256][64]         : 6291456 floats
                                                 //   (dead after apply_kernel -> reused for sample records)
#define WS_REC_OFF    WS_INBF_OFF                // records [N][8] floats (u0,v0,u1,v1,u2,v2,n,pad) : 4000000
#define WS_BIN_OFF    (WS_INBF_OFF + 6291456)    // ints: hist[4096], offs[4096]             : 8192
// total ~42.1 MB

__device__ __forceinline__ ushort_t f2bf(float f) {
  uint_t u = __float_as_uint(f);
  uint_t r = (u + 0x7fffu + ((u >> 16) & 1u)) >> 16;
  return (ushort_t)r;
}
__device__ __forceinline__ float bf2f(ushort_t u) {
  return __uint_as_float(((uint_t)u) << 16);
}
__device__ __forceinline__ int cell_of(float c0, float c1, float c2) {
  int q0 = min(15, max(0, (int)(c0 * 16.0f)));
  int q1 = min(15, max(0, (int)(c1 * 16.0f)));
  int q2 = min(15, max(0, (int)(c2 * 16.0f)));
  return (q0 << 8) | (q1 << 4) | q2;
}

// ================= prep: weights [oc][ic][3][3] fp32 -> [tap][oc][ic] bf16; zero stats + bins
__global__ __launch_bounds__(256) void wprep_kernel(const float* __restrict__ w_in,
                                                    float* __restrict__ ws) {
  int i = blockIdx.x * 256 + threadIdx.x;  // < 36864
  if (i < 36864) {
    int ic = i & 63;
    int oc = (i >> 6) & 63;
    int kk = i >> 12;  // 0..8
    ((ushort_t*)(ws + WS_WBF_OFF))[i] = f2bf(w_in[(oc * 64 + ic) * 9 + kk]);
  }
  if (i < 384) ws[WS_SUM_OFF + i] = 0.0f;
  if (i < 8192) ((int*)(ws + WS_BIN_OFF))[i] = 0;
}

// ================= bin histogram
__global__ __launch_bounds__(256) void hist_kernel(const float* __restrict__ coords,
                                                   float* __restrict__ ws) {
  int n = blockIdx.x * 256 + threadIdx.x;
  if (n >= N_POINTS) return;
  float c0 = (coords[n * 3 + 0] + 1.0f) * 0.5f;
  float c1 = (coords[n * 3 + 1] + 1.0f) * 0.5f;
  float c2 = (coords[n * 3 + 2] + 1.0f) * 0.5f;
  atomicAdd(&((int*)(ws + WS_BIN_OFF))[cell_of(c0, c1, c2)], 1);
}

// ================= exclusive scan of 4096 bins (single block)
__global__ __launch_bounds__(256) void scan_kernel(float* __restrict__ ws) {
  __shared__ int sums[256];
  int* hist = (int*)(ws + WS_BIN_OFF);
  int* offs = hist + 4096;
  int t = threadIdx.x;
  int local[16], s = 0;
#pragma unroll
  for (int k = 0; k < 16; k++) { local[k] = hist[t * 16 + k]; s += local[k]; }
  sums[t] = s;
  __syncthreads();
  for (int d = 1; d < 256; d <<= 1) {
    int v = (t >= d) ? sums[t - d] : 0;
    __syncthreads();
    sums[t] += v;
    __syncthreads();
  }
  int excl = sums[t] - s;
#pragma unroll
  for (int k = 0; k < 16; k++) { offs[t * 16 + k] = excl; excl += local[k]; }
}

// ================= scatter: permuted sample records (noise pre-added)
__global__ __launch_bounds__(256) void scatter_kernel(const float* __restrict__ coords,
                                                      const float* __restrict__ noise,
                                                      float* __restrict__ ws) {
  int n = blockIdx.x * 256 + threadIdx.x;
  if (n >= N_POINTS) return;
  float c0 = (coords[n * 3 + 0] + 1.0f) * 0.5f;
  float c1 = (coords[n * 3 + 1] + 1.0f) * 0.5f;
  float c2 = (coords[n * 3 + 2] + 1.0f) * 0.5f;
  int cell = cell_of(c0, c1, c2);
  int* offs = (int*)(ws + WS_BIN_OFF) + 4096;
  int pos = atomicAdd(&offs[cell], 1);
  float u0 = c0 + noise[(0 * N_POINTS + n) * 2 + 0];
  float v0 = c1 + noise[(0 * N_POINTS + n) * 2 + 1];
  float u1 = c1 + noise[(1 * N_POINTS + n) * 2 + 0];
  float v1 = c2 + noise[(1 * N_POINTS + n) * 2 + 1];
  float u2 = c0 + noise[(2 * N_POINTS + n) * 2 + 0];
  float v2 = c2 + noise[(2 * N_POINTS + n) * 2 + 1];
  float4* rec = (float4*)(ws + WS_REC_OFF) + pos * 2;
  rec[0] = make_float4(u0, v0, u1, v1);
  rec[1] = make_float4(u2, v2, __int_as_float(n), 0.0f);
}

// ================= transpose: input CHW fp32 -> HWC bf16
__global__ __launch_bounds__(256) void transpose_kernel(const float* __restrict__ p0,
                                                        const float* __restrict__ p1,
                                                        const float* __restrict__ p2,
                                                        float* __restrict__ ws) {
  __shared__ float tile[64][65];
  const int xt = blockIdx.x, y = blockIdx.y, pl = blockIdx.z;
  const float* src = (pl == 0) ? p0 : ((pl == 1) ? p1 : p2);
  ushort_t* dst = (ushort_t*)(ws + WS_INBF_OFF) + pl * (256 * 256 * 64);
  const int t = threadIdx.x;
  const int x0 = xt * 64;
  for (int i = t; i < 4096; i += 256) {
    int c = i >> 6, x = i & 63;
    tile[x][c] = src[(c * 256 + y) * 256 + x0 + x];
  }
  __syncthreads();
  uint_t* du = (uint_t*)dst;
  for (int i = t; i < 2048; i += 256) {
    int x = i >> 5, cp = (i & 31) * 2;
    uint_t lo = f2bf(tile[x][cp]);
    uint_t hi = f2bf(tile[x][cp + 1]);
    du[((y * 256 + x0 + x) * 64 + cp) >> 1] = (hi << 16) | lo;
  }
}

// ================= conv3x3 stride2 pad1 via MFMA bf16 (bias cancels in batch-stat BN)
__global__ __launch_bounds__(256) void conv_mfma_kernel(const float* __restrict__ ws_r,
                                                        float* __restrict__ ws) {
  const int xh = blockIdx.x, oy = blockIdx.y, pz = blockIdx.z;
  const int t = threadIdx.x;
  const int wv = t >> 6, lane = t & 63;
  const int mn = lane & 15;
  const int kg = lane >> 4;
  const int x0w = xh * 64 + wv * 16;

  const ushort_t* inb = (const ushort_t*)(ws_r + WS_INBF_OFF) + pz * (256 * 256 * 64);
  const ushort_t* wbf = (const ushort_t*)(ws_r + WS_WBF_OFF);

  floatx4 acc[4] = {{0.f,0.f,0.f,0.f},{0.f,0.f,0.f,0.f},{0.f,0.f,0.f,0.f},{0.f,0.f,0.f,0.f}};

  for (int ky = 0; ky < 3; ky++) {
    int y = 2 * oy - 1 + ky;
    if (y < 0) continue;
    const ushort_t* rowp = inb + y * (256 * 64);
    for (int kx = 0; kx < 3; kx++) {
      int xm = 2 * (x0w + mn) - 1 + kx;
      bool vx = xm >= 0;
      int xc = vx ? xm : 0;
      const ushort_t* abase = rowp + xc * 64 + kg * 8;
      const ushort_t* wbase = wbf + ((ky * 3 + kx) * 64 + mn) * 64 + kg * 8;
#pragma unroll
      for (int kc = 0; kc < 2; kc++) {
        union { int4 i4; short8 s8; } au;
        au.i4 = *reinterpret_cast<const int4*>(abase + kc * 32);
        if (!vx) au.i4 = make_int4(0, 0, 0, 0);
#pragma unroll
        for (int nt = 0; nt < 4; nt++) {
          union { int4 i4; short8 s8; } bu;
          bu.i4 = *reinterpret_cast<const int4*>(wbase + nt * 1024 + kc * 32);
          acc[nt] = __builtin_amdgcn_mfma_f32_16x16x32_bf16(au.s8, bu.s8, acc[nt], 0, 0, 0);
        }
      }
    }
  }
  float* cout = ws + WS_CONV_OFF + ((pz * 128 + oy) * 128 + x0w) * 64;
#pragma unroll
  for (int nt = 0; nt < 4; nt++) {
#pragma unroll
    for (int r = 0; r < 4; r++) {
      cout[(kg * 4 + r) * 64 + nt * 16 + mn] = acc[nt][r];
    }
  }
}

// ================= BN stats
__global__ __launch_bounds__(256) void stats_kernel(float* __restrict__ ws) {
  const int b = blockIdx.x;
  const int plane = b >> 6, chunk = b & 63;
  const int t = threadIdx.x;
  const int c = t & 63, g = t >> 6;
  const float* base = ws + WS_CONV_OFF + plane * (16384 * 64);
  float s = 0.0f, s2 = 0.0f;
  const int row0 = chunk * 256 + g * 64;
  for (int i = 0; i < 64; i++) {
    float v = base[(row0 + i) * 64 + c];
    s += v;
    s2 = fmaf(v, v, s2);
  }
  __shared__ float rs[256], rs2[256];
  rs[t] = s; rs2[t] = s2;
  __syncthreads();
  if (t < 64) {
    s = rs[t] + rs[t + 64] + rs[t + 128] + rs[t + 192];
    s2 = rs2[t] + rs2[t + 64] + rs2[t + 128] + rs2[t + 192];
    atomicAdd(&ws[WS_SUM_OFF + plane * 64 + c], s);
    atomicAdd(&ws[WS_SUMSQ_OFF + plane * 64 + c], s2);
  }
}

__global__ void finalize_kernel(const float* __restrict__ gamma,
                                const float* __restrict__ beta,
                                float* __restrict__ ws) {
  int i = threadIdx.x;
  if (i < 192) {
    int c = i & 63;
    float mu = ws[WS_SUM_OFF + i] * (1.0f / 16384.0f);
    float var = ws[WS_SUMSQ_OFF + i] * (1.0f / 16384.0f) - mu * mu;
    var = fmaxf(var, 0.0f);
    float rstd = 1.0f / sqrtf(var + BN_EPS);
    float sc = gamma[c] * rstd;
    ws[WS_SCALE_OFF + i] = sc;
    ws[WS_SHIFT_OFF + i] = beta[c] - mu * sc;
  }
}

// ================= apply BN + relu + fused avgpool + pack fp16
__global__ __launch_bounds__(256) void apply_kernel(float* __restrict__ ws,
                                                    __half* __restrict__ planes) {
  int idx = blockIdx.x * 256 + threadIdx.x;  // < 393216
  int g = idx & 7;
  int p = (idx >> 3) & 16383;
  int pl = idx >> 17;
  int oy = p >> 7, ox = p & 127;
  int cb = g * 8;

  const float* conv = ws + WS_CONV_OFF;
  float4 a0 = *reinterpret_cast<const float4*>(conv + (size_t)idx * 8);
  float4 a1 = *reinterpret_cast<const float4*>(conv + (size_t)idx * 8 + 4);

  float sc[8], sh[8];
#pragma unroll
  for (int k = 0; k < 8; k++) {
    sc[k] = ws[WS_SCALE_OFF + pl * 64 + cb + k];
    sh[k] = ws[WS_SHIFT_OFF + pl * 64 + cb + k];
  }

  const ushort_t* inb = (const ushort_t*)(ws + WS_INBF_OFF) + pl * (256 * 256 * 64);
  float ps[8];
#pragma unroll
  for (int k = 0; k < 8; k++) ps[k] = 0.0f;
#pragma unroll
  for (int r = 0; r < 3; r++) {
    int yy = 2 * oy - 1 + r;
    if (yy < 0) continue;
#pragma unroll
    for (int s = 0; s < 3; s++) {
      int xx = 2 * ox - 1 + s;
      if (xx < 0) continue;
      union { int4 i4; ushort_t u[8]; } ub;
      ub.i4 = *reinterpret_cast<const int4*>(inb + (yy * 256 + xx) * 64 + cb);
#pragma unroll
      for (int k = 0; k < 8; k++) ps[k] += bf2f(ub.u[k]);
    }
  }

  float v[8] = {a0.x, a0.y, a0.z, a0.w, a1.x, a1.y, a1.z, a1.w};
  union { int4 i4; __half h[8]; } ob;
#pragma unroll
  for (int k = 0; k < 8; k++) {
    float r = fmaxf(fmaf(v[k], sc[k], sh[k]), 0.0f) + ps[k] * (1.0f / 9.0f);
    ob.h[k] = __float2half(r);
  }
  *reinterpret_cast<int4*>(planes + (size_t)idx * 8) = ob.i4;
}

// ================= bicubic sampling (records in cell order; v_fma_mix accumulation)
__device__ __forceinline__ void cubic_w(float t, float w[4]) {
  float t1 = t + 1.0f;
  w[0] = ((A_COEF * t1 - 5.0f * A_COEF) * t1 + 8.0f * A_COEF) * t1 - 4.0f * A_COEF;
  w[1] = ((A_COEF + 2.0f) * t - (A_COEF + 3.0f)) * t * t + 1.0f;
  float s = 1.0f - t;
  w[2] = ((A_COEF + 2.0f) * s - (A_COEF + 3.0f)) * s * s + 1.0f;
  w[3] = 1.0f - w[0] - w[1] - w[2];
}

__global__ __launch_bounds__(256) void sample_kernel(const float* __restrict__ ws,
                                                     const __half* __restrict__ planes,
                                                     float* __restrict__ out) {
  const int t = threadIdx.x;
  const int wv = t >> 6, lane = t & 63;
  const int g = lane >> 3, l = lane & 7;
  const int idx = blockIdx.x * 32 + wv * 8 + g;

  const float4* rec = (const float4*)(ws + WS_REC_OFF) + (size_t)idx * 2;
  float4 r0 = rec[0];
  float4 r1 = rec[1];
  const int n = __float_as_int(r1.z);
  float uu[3] = {r0.x, r0.z, r1.x};
  float vv[3] = {r0.y, r0.w, r1.y};

  float acc[8];
#pragma unroll
  for (int e = 0; e < 8; e++) acc[e] = 0.0f;

  const char* pbase = (const char*)planes + l * 16;

#pragma unroll
  for (int p = 0; p < 3; p++) {
    float gx = fminf(fmaxf(fmaf(uu[p], 63.5f, 63.5f), 0.0f), 127.0f);
    float gy = fminf(fmaxf(fmaf(vv[p], 63.5f, 63.5f), 0.0f), 127.0f);
    float x0f = floorf(gx), y0f = floorf(gy);
    float tx = gx - x0f, ty = gy - y0f;
    int ix = (int)x0f, iy = (int)y0f;
    float wx[4], wy[4];
    cubic_w(tx, wx);
    cubic_w(ty, wy);
    // precompute clamped byte offsets (row = 128 px * 128 B = 16384 B; col = 128 B)
    uint_t yo[4], xo[4];
#pragma unroll
    for (int i = 0; i < 4; i++) yo[i] = (uint_t)min(max(iy - 1 + i, 0), 127) * 16384u;
#pragma unroll
    for (int j = 0; j < 4; j++) xo[j] = (uint_t)min(max(ix - 1 + j, 0), 127) * 128u;
    const char* pb = pbase + (size_t)p * 2097152;
#pragma unroll
    for (int i = 0; i < 4; i++) {
      const char* rp = pb + yo[i];
#pragma unroll
      for (int j = 0; j < 4; j++) {
        union { int4 i4; __half h[8]; } ub;
        ub.i4 = *reinterpret_cast<const int4*>(rp + xo[j]);
        float w = wy[i] * wx[j];
#pragma unroll
        for (int q = 0; q < 8; q++) {
          acc[q] = fmaf(__half2float(ub.h[q]), w, acc[q]);  // -> v_fma_mix_f32
        }
      }
    }
  }
  float4* op = reinterpret_cast<float4*>(out + (size_t)n * 64 + l * 8);
  op[0] = make_float4(acc[0], acc[1], acc[2], acc[3]);
  op[1] = make_float4(acc[4], acc[5], acc[6], acc[7]);
}

extern "C" void kernel_launch(void* const* d_in, const int* in_sizes, int n_in,
                              void* d_out, int out_size, void* d_ws, size_t ws_size,
                              hipStream_t stream) {
  const float* coords = (const float*)d_in[0];
  const float* noise  = (const float*)d_in[1];
  const float* px     = (const float*)d_in[2];
  const float* py     = (const float*)d_in[3];
  const float* pz     = (const float*)d_in[4];
  const float* conv_w = (const float*)d_in[5];
  // conv_b unused: bias cancels exactly under batch-stat BN
  const float* gamma  = (const float*)d_in[7];
  const float* beta   = (const float*)d_in[8];
  float* out = (float*)d_out;
  float* ws = (float*)d_ws;
  __half* planes = (__half*)(ws + WS_PLANES_OFF);

  wprep_kernel<<<144, 256, 0, stream>>>(conv_w, ws);
  hist_kernel<<<1954, 256, 0, stream>>>(coords, ws);
  scan_kernel<<<1, 256, 0, stream>>>(ws);
  transpose_kernel<<<dim3(4, 256, 3), 256, 0, stream>>>(px, py, pz, ws);
  conv_mfma_kernel<<<dim3(2, 128, 3), 256, 0, stream>>>(ws, ws);
  stats_kernel<<<192, 256, 0, stream>>>(ws);
  finalize_kernel<<<1, 256, 0, stream>>>(gamma, beta, ws);
  apply_kernel<<<1536, 256, 0, stream>>>(ws, planes);
  scatter_kernel<<<1954, 256, 0, stream>>>(coords, noise, ws);  // overlays INBF (dead after apply)
  sample_kernel<<<15625, 256, 0, stream>>>(ws, planes, out);
}

// Round 4
// 392.680 us; speedup vs baseline: 1.0547x; 1.0547x over previous
//
#include <hip/hip_runtime.h>
#include <hip/hip_fp16.h>

#define N_POINTS 500000
#define BN_EPS 1e-5f
#define A_COEF -0.75f

typedef __attribute__((ext_vector_type(8))) short short8;
typedef __attribute__((ext_vector_type(4))) float floatx4;
typedef unsigned short ushort_t;
typedef unsigned int uint_t;

// -------- workspace layout (float offsets) --------
#define WS_WBF_OFF    0                          // bf16 weights, MFMA-frag order [tap][kc][nt][lane][j] : 18432 floats
#define WS_CONV_OFF   18432                      // conv HWC fp32 [3][128][128][64] : 3145728
#define WS_PLANES_OFF (WS_CONV_OFF + 3145728)    // fp16 planes HWC [3][128][128][64] : 1572864 floats
#define WS_INBF_OFF   (WS_PLANES_OFF + 1572864)  // bf16 input HWC [3][256][256][64] : 6291456 floats
#define WS_REC_OFF    WS_INBF_OFF                // records overlay (dead after apply)
#define WS_SUM_OFF    (WS_INBF_OFF + 6291456)    // ---- zero-cluster start (one memset) ----
#define WS_SUMSQ_OFF  (WS_SUM_OFF + 192)
#define WS_HIST_OFF   (WS_SUMSQ_OFF + 192)       // 4096 ints
#define WS_OFFS_OFF   (WS_HIST_OFF + 4096)       // 4096 ints  ---- zero-cluster end (8576 words) ----
#define WS_SCALE_OFF  (WS_OFFS_OFF + 4096)
#define WS_SHIFT_OFF  (WS_SCALE_OFF + 192)
// total 11037440 floats = 44.15 MB (same footprint as R3, which allocated fine)

__device__ __forceinline__ ushort_t f2bf(float f) {
  uint_t u = __float_as_uint(f);
  uint_t r = (u + 0x7fffu + ((u >> 16) & 1u)) >> 16;
  return (ushort_t)r;
}
__device__ __forceinline__ float bf2f(ushort_t u) {
  return __uint_as_float(((uint_t)u) << 16);
}
__device__ __forceinline__ int cell_of(float c0, float c1, float c2) {
  int q0 = min(15, max(0, (int)(c0 * 16.0f)));
  int q1 = min(15, max(0, (int)(c1 * 16.0f)));
  int q2 = min(15, max(0, (int)(c2 * 16.0f)));
  return (q0 << 8) | (q1 << 4) | q2;
}

// ================= fused: transpose CHW fp32 -> HWC bf16  +  weight pack  +  point histogram
// grid (4,256,3); flat bid in [0,3072)
__global__ __launch_bounds__(256) void prep_kernel(const float* __restrict__ p0,
                                                   const float* __restrict__ p1,
                                                   const float* __restrict__ p2,
                                                   const float* __restrict__ w_in,
                                                   const float* __restrict__ coords,
                                                   float* __restrict__ ws) {
  __shared__ float tile[64][65];
  const int xt = blockIdx.x, y = blockIdx.y, pl = blockIdx.z;
  const int bid = (pl * 256 + y) * 4 + xt;
  const int t = threadIdx.x;

  // ---- side-job A: histogram (bins zeroed by preceding memset) ----
  if (bid < 1954) {
    int n = bid * 256 + t;
    if (n < N_POINTS) {
      float c0 = (coords[n * 3 + 0] + 1.0f) * 0.5f;
      float c1 = (coords[n * 3 + 1] + 1.0f) * 0.5f;
      float c2 = (coords[n * 3 + 2] + 1.0f) * 0.5f;
      atomicAdd(&((int*)(ws + WS_HIST_OFF))[cell_of(c0, c1, c2)], 1);
    }
  }
  // ---- side-job B: weight pack into MFMA B-fragment lane order ----
  // i = (((tap*2+kc)*4+nt)*64+lane)*8+j ; element = W[oc=nt*16+(lane&15)][ic=kc*32+(lane>>4)*8+j][tap]
  if (bid >= 2048 && bid < 2192) {
    int i = (bid - 2048) * 256 + t;  // < 36864
    int j = i & 7;
    int lane = (i >> 3) & 63;
    int nt = (i >> 9) & 3;
    int kc = (i >> 11) & 1;
    int tap = i >> 12;
    int oc = nt * 16 + (lane & 15);
    int ic = kc * 32 + (lane >> 4) * 8 + j;
    ((ushort_t*)(ws + WS_WBF_OFF))[i] = f2bf(w_in[(oc * 64 + ic) * 9 + tap]);
  }

  // ---- main job: 64x64 transpose tile ----
  const float* src = (pl == 0) ? p0 : ((pl == 1) ? p1 : p2);
  ushort_t* dst = (ushort_t*)(ws + WS_INBF_OFF) + pl * (256 * 256 * 64);
  const int x0 = xt * 64;
  for (int i = t; i < 4096; i += 256) {
    int c = i >> 6, x = i & 63;
    tile[x][c] = src[(c * 256 + y) * 256 + x0 + x];
  }
  __syncthreads();
  uint_t* du = (uint_t*)dst;
  for (int i = t; i < 2048; i += 256) {
    int x = i >> 5, cp = (i & 31) * 2;
    uint_t lo = f2bf(tile[x][cp]);
    uint_t hi = f2bf(tile[x][cp + 1]);
    du[((y * 256 + x0 + x) * 64 + cp) >> 1] = (hi << 16) | lo;
  }
}

// ================= conv3x3 stride2 pad1 via MFMA bf16 + fused BN-stats reduction
// grid (2,128,3). wave computes 16 px x 64 oc. B-loads fully coalesced (frag-order pack).
__global__ __launch_bounds__(256) void conv_mfma_kernel(const float* __restrict__ ws_r,
                                                        float* __restrict__ ws) {
  __shared__ float reds[16][64];
  __shared__ float redq[16][64];
  const int xh = blockIdx.x, oy = blockIdx.y, pz = blockIdx.z;
  const int t = threadIdx.x;
  const int wv = t >> 6, lane = t & 63;
  const int mn = lane & 15;
  const int kg = lane >> 4;
  const int x0w = xh * 64 + wv * 16;

  const ushort_t* inb = (const ushort_t*)(ws_r + WS_INBF_OFF) + pz * (256 * 256 * 64);
  const ushort_t* wbf = (const ushort_t*)(ws_r + WS_WBF_OFF);

  floatx4 acc[4] = {{0.f,0.f,0.f,0.f},{0.f,0.f,0.f,0.f},{0.f,0.f,0.f,0.f},{0.f,0.f,0.f,0.f}};

  for (int ky = 0; ky < 3; ky++) {
    int y = 2 * oy - 1 + ky;
    if (y < 0) continue;
    const ushort_t* rowp = inb + y * (256 * 64);
    for (int kx = 0; kx < 3; kx++) {
      int xm = 2 * (x0w + mn) - 1 + kx;
      bool vx = xm >= 0;
      int xc = vx ? xm : 0;
      const ushort_t* abase = rowp + xc * 64 + kg * 8;
      const int tap = ky * 3 + kx;
#pragma unroll
      for (int kc = 0; kc < 2; kc++) {
        union { int4 i4; short8 s8; } au;
        au.i4 = *reinterpret_cast<const int4*>(abase + kc * 32);
        if (!vx) au.i4 = make_int4(0, 0, 0, 0);
#pragma unroll
        for (int nt = 0; nt < 4; nt++) {
          union { int4 i4; short8 s8; } bu;
          bu.i4 = *reinterpret_cast<const int4*>(wbf + ((((tap * 2 + kc) * 4 + nt) * 64 + lane) << 3));
          acc[nt] = __builtin_amdgcn_mfma_f32_16x16x32_bf16(au.s8, bu.s8, acc[nt], 0, 0, 0);
        }
      }
    }
  }
  // D: col(oc) = lane&15, row(px) = kg*4 + reg
  float* cout = ws + WS_CONV_OFF + ((pz * 128 + oy) * 128 + x0w) * 64;
#pragma unroll
  for (int nt = 0; nt < 4; nt++) {
    float s = 0.0f, s2 = 0.0f;
#pragma unroll
    for (int r = 0; r < 4; r++) {
      float v = acc[nt][r];
      cout[(kg * 4 + r) * 64 + nt * 16 + mn] = v;
      s += v;
      s2 = fmaf(v, v, s2);
    }
    reds[wv * 4 + kg][nt * 16 + mn] = s;
    redq[wv * 4 + kg][nt * 16 + mn] = s2;
  }
  __syncthreads();
  if (t < 64) {
    float s = 0.0f, s2 = 0.0f;
#pragma unroll
    for (int r = 0; r < 16; r++) { s += reds[r][t]; s2 += redq[r][t]; }
    atomicAdd(&ws[WS_SUM_OFF + pz * 64 + t], s);
    atomicAdd(&ws[WS_SUMSQ_OFF + pz * 64 + t], s2);
  }
}

// ================= fused: exclusive scan of 4096 bins + BN finalize (single block)
__global__ __launch_bounds__(256) void scanfin_kernel(const float* __restrict__ gamma,
                                                      const float* __restrict__ beta,
                                                      float* __restrict__ ws) {
  __shared__ int sums[256];
  int* hist = (int*)(ws + WS_HIST_OFF);
  int* offs = (int*)(ws + WS_OFFS_OFF);
  int t = threadIdx.x;
  int local[16], s = 0;
#pragma unroll
  for (int k = 0; k < 16; k++) { local[k] = hist[t * 16 + k]; s += local[k]; }
  sums[t] = s;
  __syncthreads();
  for (int d = 1; d < 256; d <<= 1) {
    int v = (t >= d) ? sums[t - d] : 0;
    __syncthreads();
    sums[t] += v;
    __syncthreads();
  }
  int excl = sums[t] - s;
#pragma unroll
  for (int k = 0; k < 16; k++) { offs[t * 16 + k] = excl; excl += local[k]; }

  if (t < 192) {
    int c = t & 63;
    float mu = ws[WS_SUM_OFF + t] * (1.0f / 16384.0f);
    float var = ws[WS_SUMSQ_OFF + t] * (1.0f / 16384.0f) - mu * mu;
    var = fmaxf(var, 0.0f);
    float rstd = 1.0f / sqrtf(var + BN_EPS);
    float sc = gamma[c] * rstd;
    ws[WS_SCALE_OFF + t] = sc;
    ws[WS_SHIFT_OFF + t] = beta[c] - mu * sc;
  }
}

// ================= apply BN + relu + fused avgpool + pack fp16
__global__ __launch_bounds__(256) void apply_kernel(float* __restrict__ ws,
                                                    __half* __restrict__ planes) {
  int idx = blockIdx.x * 256 + threadIdx.x;  // < 393216
  int g = idx & 7;
  int p = (idx >> 3) & 16383;
  int pl = idx >> 17;
  int oy = p >> 7, ox = p & 127;
  int cb = g * 8;

  const float* conv = ws + WS_CONV_OFF;
  float4 a0 = *reinterpret_cast<const float4*>(conv + (size_t)idx * 8);
  float4 a1 = *reinterpret_cast<const float4*>(conv + (size_t)idx * 8 + 4);

  float sc[8], sh[8];
#pragma unroll
  for (int k = 0; k < 8; k++) {
    sc[k] = ws[WS_SCALE_OFF + pl * 64 + cb + k];
    sh[k] = ws[WS_SHIFT_OFF + pl * 64 + cb + k];
  }

  const ushort_t* inb = (const ushort_t*)(ws + WS_INBF_OFF) + pl * (256 * 256 * 64);
  float ps[8];
#pragma unroll
  for (int k = 0; k < 8; k++) ps[k] = 0.0f;
#pragma unroll
  for (int r = 0; r < 3; r++) {
    int yy = 2 * oy - 1 + r;
    if (yy < 0) continue;
#pragma unroll
    for (int s = 0; s < 3; s++) {
      int xx = 2 * ox - 1 + s;
      if (xx < 0) continue;
      union { int4 i4; ushort_t u[8]; } ub;
      ub.i4 = *reinterpret_cast<const int4*>(inb + (yy * 256 + xx) * 64 + cb);
#pragma unroll
      for (int k = 0; k < 8; k++) ps[k] += bf2f(ub.u[k]);
    }
  }

  float v[8] = {a0.x, a0.y, a0.z, a0.w, a1.x, a1.y, a1.z, a1.w};
  union { int4 i4; __half h[8]; } ob;
#pragma unroll
  for (int k = 0; k < 8; k++) {
    float r = fmaxf(fmaf(v[k], sc[k], sh[k]), 0.0f) + ps[k] * (1.0f / 9.0f);
    ob.h[k] = __float2half(r);
  }
  *reinterpret_cast<int4*>(planes + (size_t)idx * 8) = ob.i4;
}

// ================= scatter: permuted sample records (noise pre-added); overlays INBF (dead)
__global__ __launch_bounds__(256) void scatter_kernel(const float* __restrict__ coords,
                                                      const float* __restrict__ noise,
                                                      float* __restrict__ ws) {
  int n = blockIdx.x * 256 + threadIdx.x;
  if (n >= N_POINTS) return;
  float c0 = (coords[n * 3 + 0] + 1.0f) * 0.5f;
  float c1 = (coords[n * 3 + 1] + 1.0f) * 0.5f;
  float c2 = (coords[n * 3 + 2] + 1.0f) * 0.5f;
  int cell = cell_of(c0, c1, c2);
  int pos = atomicAdd(&((int*)(ws + WS_OFFS_OFF))[cell], 1);
  float u0 = c0 + noise[(0 * N_POINTS + n) * 2 + 0];
  float v0 = c1 + noise[(0 * N_POINTS + n) * 2 + 1];
  float u1 = c1 + noise[(1 * N_POINTS + n) * 2 + 0];
  float v1 = c2 + noise[(1 * N_POINTS + n) * 2 + 1];
  float u2 = c0 + noise[(2 * N_POINTS + n) * 2 + 0];
  float v2 = c2 + noise[(2 * N_POINTS + n) * 2 + 1];
  float4* rec = (float4*)(ws + WS_REC_OFF) + pos * 2;
  rec[0] = make_float4(u0, v0, u1, v1);
  rec[1] = make_float4(u2, v2, __int_as_float(n), 0.0f);
}

// ================= bicubic sampling: pk_fma_f16 row accumulation + fma_mix into f32
__device__ __forceinline__ void cubic_w(float t, float w[4]) {
  float t1 = t + 1.0f;
  w[0] = ((A_COEF * t1 - 5.0f * A_COEF) * t1 + 8.0f * A_COEF) * t1 - 4.0f * A_COEF;
  w[1] = ((A_COEF + 2.0f) * t - (A_COEF + 3.0f)) * t * t + 1.0f;
  float s = 1.0f - t;
  w[2] = ((A_COEF + 2.0f) * s - (A_COEF + 3.0f)) * s * s + 1.0f;
  w[3] = 1.0f - w[0] - w[1] - w[2];
}

__global__ __launch_bounds__(256) void sample_kernel(const float* __restrict__ ws,
                                                     const __half* __restrict__ planes,
                                                     float* __restrict__ out) {
  const int t = threadIdx.x;
  const int wv = t >> 6, lane = t & 63;
  const int g = lane >> 3, l = lane & 7;
  const int idx = blockIdx.x * 32 + wv * 8 + g;

  const float4* rec = (const float4*)(ws + WS_REC_OFF) + (size_t)idx * 2;
  float4 r0 = rec[0];
  float4 r1 = rec[1];
  const int n = __float_as_int(r1.z);
  float uu[3] = {r0.x, r0.z, r1.x};
  float vv[3] = {r0.y, r0.w, r1.y};

  float facc[8];
#pragma unroll
  for (int e = 0; e < 8; e++) facc[e] = 0.0f;

  const char* pbase = (const char*)planes + l * 16;

#pragma unroll
  for (int p = 0; p < 3; p++) {
    float gx = fminf(fmaxf(fmaf(uu[p], 63.5f, 63.5f), 0.0f), 127.0f);
    float gy = fminf(fmaxf(fmaf(vv[p], 63.5f, 63.5f), 0.0f), 127.0f);
    float x0f = floorf(gx), y0f = floorf(gy);
    float tx = gx - x0f, ty = gy - y0f;
    int ix = (int)x0f, iy = (int)y0f;
    float wx[4], wy[4];
    cubic_w(tx, wx);
    cubic_w(ty, wy);
    uint_t yo[4], xo[4];
#pragma unroll
    for (int i = 0; i < 4; i++) yo[i] = (uint_t)min(max(iy - 1 + i, 0), 127) * 16384u;
#pragma unroll
    for (int j = 0; j < 4; j++) xo[j] = (uint_t)min(max(ix - 1 + j, 0), 127) * 128u;
    __half2 wxh[4];
#pragma unroll
    for (int j = 0; j < 4; j++) wxh[j] = __float2half2_rn(wx[j]);
    const char* pb = pbase + (size_t)p * 2097152;
#pragma unroll
    for (int i = 0; i < 4; i++) {
      const char* rp = pb + yo[i];
      __half2 r2[4];
#pragma unroll
      for (int q = 0; q < 4; q++) r2[q] = __float2half2_rn(0.0f);
#pragma unroll
      for (int j = 0; j < 4; j++) {
        union { int4 i4; __half2 h2[4]; } ub;
        ub.i4 = *reinterpret_cast<const int4*>(rp + xo[j]);
#pragma unroll
        for (int q = 0; q < 4; q++) r2[q] = __hfma2(ub.h2[q], wxh[j], r2[q]);
      }
      float wyv = wy[i];
#pragma unroll
      for (int q = 0; q < 4; q++) {
        facc[2 * q]     = fmaf(__low2float(r2[q]),  wyv, facc[2 * q]);      // v_fma_mix
        facc[2 * q + 1] = fmaf(__high2float(r2[q]), wyv, facc[2 * q + 1]);
      }
    }
  }
  float4* op = reinterpret_cast<float4*>(out + (size_t)n * 64 + l * 8);
  op[0] = make_float4(facc[0], facc[1], facc[2], facc[3]);
  op[1] = make_float4(facc[4], facc[5], facc[6], facc[7]);
}

extern "C" void kernel_launch(void* const* d_in, const int* in_sizes, int n_in,
                              void* d_out, int out_size, void* d_ws, size_t ws_size,
                              hipStream_t stream) {
  const float* coords = (const float*)d_in[0];
  const float* noise  = (const float*)d_in[1];
  const float* px     = (const float*)d_in[2];
  const float* py     = (const float*)d_in[3];
  const float* pz     = (const float*)d_in[4];
  const float* conv_w = (const float*)d_in[5];
  // conv_b unused: bias cancels exactly under batch-stat BN
  const float* gamma  = (const float*)d_in[7];
  const float* beta   = (const float*)d_in[8];
  float* out = (float*)d_out;
  float* ws = (float*)d_ws;
  __half* planes = (__half*)(ws + WS_PLANES_OFF);

  hipMemsetAsync(ws + WS_SUM_OFF, 0, 8576 * sizeof(float), stream);  // stats + hist + offs
  prep_kernel<<<dim3(4, 256, 3), 256, 0, stream>>>(px, py, pz, conv_w, coords, ws);
  conv_mfma_kernel<<<dim3(2, 128, 3), 256, 0, stream>>>(ws, ws);
  scanfin_kernel<<<1, 256, 0, stream>>>(gamma, beta, ws);
  apply_kernel<<<1536, 256, 0, stream>>>(ws, planes);
  scatter_kernel<<<1954, 256, 0, stream>>>(coords, noise, ws);
  sample_kernel<<<15625, 256, 0, stream>>>(ws, planes, out);
}